// Round 4
// baseline (133.226 us; speedup 1.0000x reference)
//
#include <hip/hip_runtime.h>

#define S_TOT 37448
#define OUT_T 5704
#define EMB 256

typedef unsigned short u16;
typedef __bf16 bf16x8 __attribute__((ext_vector_type(8)));
typedef float f32x4 __attribute__((ext_vector_type(4)));
typedef unsigned short u16x4 __attribute__((ext_vector_type(4)));
typedef unsigned short u16x8 __attribute__((ext_vector_type(8)));

__device__ __forceinline__ u16 f2bf(float f) {
  union { float f; unsigned int i; } v;
  v.f = f;
  unsigned int x = v.i;
  return (u16)((x + 0x7fffu + ((x >> 16) & 1u)) >> 16);
}

#define GLOAD_LDS16(g, l)                                                     \
  __builtin_amdgcn_global_load_lds((const __attribute__((address_space(1))) void*)(g), \
                                   (__attribute__((address_space(3))) void*)(l), 16, 0, 0)

// ---------------- layers 0-2: pure embedding gather (f32, exact) ------------
__global__ __launch_bounds__(256) void emb_small(
    const int* __restrict__ value, const int* __restrict__ depth,
    const int* __restrict__ position,
    const float* __restrict__ ve0, const float* __restrict__ pe0, const float* __restrict__ de0,
    const float* __restrict__ ve1, const float* __restrict__ pe1, const float* __restrict__ de1,
    const float* __restrict__ ve2, const float* __restrict__ pe2, const float* __restrict__ de2,
    float* __restrict__ out) {
  const int tok = blockIdx.x;
  const int b = tok / 584;
  const int t = tok - b * 584;
  const float *ve, *pe, *de;
  if (t < 8)       { ve = ve0; pe = pe0; de = de0; }
  else if (t < 72) { ve = ve1; pe = pe1; de = de1; }
  else             { ve = ve2; pe = pe2; de = de2; }
  const long base = (long)b * S_TOT + t;
  const int v = value[base];
  const int d = depth[base];
  const int p0 = position[base * 3 + 0];
  const int p1 = position[base * 3 + 1];
  const int p2 = position[base * 3 + 2];
  const int e = threadIdx.x;
  const float sum = ve[v * EMB + e] + pe[p0 * EMB + e] +
                    pe[(64 + p1) * EMB + e] + pe[(128 + p2) * EMB + e] +
                    de[d * EMB + e];
  out[((long)b * OUT_T + t) * EMB + e] = sum;
}

// ------- W repack: f32 (O,E,k) -> bf16 Wt[o][kk*256+e] ----------------------
__global__ __launch_bounds__(256) void transpose_w(
    const float* __restrict__ w3, const float* __restrict__ w4,
    u16* __restrict__ wt3, u16* __restrict__ wt4) {
  const int i = blockIdx.x * 256 + threadIdx.x;
  if (i < 256 * 1024) {
    const int o = i >> 10, c = i & 1023, kk = c >> 8, e = c & 255;
    wt3[i] = f2bf(w3[o * 1024 + e * 4 + kk]);
  }
  if (i < 256 * 2048) {
    const int o = i >> 11, c = i & 2047, kk = c >> 8, e = c & 255;
    wt4[i] = f2bf(w4[o * 2048 + e * 8 + kk]);
  }
}

// ---------------- fused gather + GEMM, pipelined, 8 waves -------------------
// BM=64, BN=256, BK=32. 512 threads = 8 waves (2 row-groups x 4 col-groups);
// wave tile 32x64 -> acc[2][4], 8 MFMA/step. Double-buffered LDS, XOR granule
// swizzle g ^= (row>>1)&3 on 16B granules (both sides -> <=2-way, free).
template <int K, int LOG2T, int CK, int S0, int OUT0>
__device__ __forceinline__ void conv_tile(
    int bid, const int* __restrict__ value, const int* __restrict__ position,
    const float* __restrict__ ve, const float* __restrict__ pe,
    const u16* __restrict__ wt, const float* __restrict__ wraw,
    const float* __restrict__ bias, float* __restrict__ out,
    u16 (*As)[64 * 32], u16 (*Bs)[256 * 32], unsigned* idxc) {
  constexpr int T = 1 << LOG2T;
  constexpr int NS = K / 32;
  const int tid = threadIdx.x;
  const int lane = tid & 63;
  const int wid = tid >> 6;   // 0..7
  const int wr = wid >> 2;    // 0..1 row-group
  const int wc = wid & 3;     // 0..3 col-group
  const int fr = lane & 15;
  const int fq = lane >> 4;   // 0..3
  const int row0 = bid * 64;

  // ---- prologue: cache packed (v,p0,p1,p2) for this block's rows ----
  for (int e = tid; e < 64 * CK; e += 512) {
    const int r = e / CK, kk = e % CK;
    const int grow = row0 + r;
    const int b = grow >> LOG2T;
    const int to = grow & (T - 1);
    const long sidx = (long)b * S_TOT + (S0 + to * CK + kk);
    const unsigned v = (unsigned)value[sidx];
    const int* pp = position + sidx * 3;
    idxc[e] = v | ((unsigned)pp[0] << 8) | ((unsigned)pp[1] << 16) |
              ((unsigned)pp[2] << 24);
  }
  __syncthreads();

  // A-staging: 8 threads per row, 4 cols each
  const int arow = tid >> 3;          // 0..63
  const int acg = tid & 7;            // 4-col group 0..7
  const int agran = acg >> 1, ahalf = acg & 1;
  const int aoff = arow * 32 + (agran ^ ((arow >> 1) & 3)) * 8 + ahalf * 4;

  auto gatherA = [&](int s, float4& r) {
    const int kk = s >> 3;
    const int e0 = (s & 7) * 32 + acg * 4;
    const unsigned q = idxc[arow * CK + kk];
    const int v = q & 255, p0 = (q >> 8) & 255, p1 = (q >> 16) & 255, p2 = q >> 24;
    float4 x = *(const float4*)(ve + v * EMB + e0);
    float4 y = *(const float4*)(pe + p0 * EMB + e0);
    float4 z = *(const float4*)(pe + (64 + p1) * EMB + e0);
    float4 u = *(const float4*)(pe + (128 + p2) * EMB + e0);
    r.x = x.x + y.x + z.x + u.x;
    r.y = x.y + y.y + z.y + u.y;
    r.z = x.z + y.z + z.z + u.z;
    r.w = x.w + y.w + z.w + u.w;
  };
  auto writeA = [&](int buf, const float4& r) {
    u16x4 p;
    p[0] = f2bf(r.x); p[1] = f2bf(r.y); p[2] = f2bf(r.z); p[3] = f2bf(r.w);
    *(u16x4*)(&As[buf][aoff]) = p;
  };

  auto issueB = [&](int s, int buf) {
    if (wt) {
#pragma unroll
      for (int j = 0; j < 2; ++j) {
        const int rl = j * 128 + wid * 16 + (lane >> 2);
        const int sl = lane & 3;
        const int gc = sl ^ ((rl >> 1) & 3);  // pre-swizzled SOURCE
        const u16* src = wt + (long)rl * K + s * 32 + gc * 8;
        u16* dst = &Bs[buf][(j * 128 + wid * 16) * 32];  // linear dest
        GLOAD_LDS16(src, dst);
      }
    } else {
      const int o = tid >> 1;           // 2 threads per row
      const int hr = tid & 1;           // granule pair select
      const int kk = s >> 3, e0 = (s & 7) * 32;
      const int osw = (o >> 1) & 3;
#pragma unroll
      for (int g2 = 0; g2 < 2; ++g2) {
        const int g = hr * 2 + g2;
        u16x8 r;
#pragma unroll
        for (int c = 0; c < 8; ++c)
          r[c] = f2bf(wraw[(long)o * (EMB * CK) + (e0 + g * 8 + c) * CK + kk]);
        *(u16x8*)(&Bs[buf][o * 32 + (g ^ osw) * 8]) = r;
      }
    }
  };

  f32x4 acc[2][4];
#pragma unroll
  for (int m = 0; m < 2; ++m)
#pragma unroll
    for (int n = 0; n < 4; ++n) acc[m][n] = (f32x4){0.f, 0.f, 0.f, 0.f};

  // prologue stage of step 0
  {
    float4 a0;
    gatherA(0, a0);
    issueB(0, 0);
    writeA(0, a0);
  }
  __syncthreads();

  int cur = 0;
  for (int s = 0; s < NS; ++s) {
    const int nxt = cur ^ 1;
    const bool more = (s + 1 < NS);
    float4 pa;
    if (more) {
      gatherA(s + 1, pa);   // table loads (regs) — overlap MFMA phase
      issueB(s + 1, nxt);   // async B -> LDS buf[nxt]
    }
    bf16x8 af[2], bfv[4];
#pragma unroll
    for (int m = 0; m < 2; ++m) {
      const int r = wr * 32 + m * 16 + fr;
      u16x8 t = *(const u16x8*)(&As[cur][r * 32 + (fq ^ ((r >> 1) & 3)) * 8]);
      af[m] = __builtin_bit_cast(bf16x8, t);
    }
#pragma unroll
    for (int n = 0; n < 4; ++n) {
      const int o = wc * 64 + n * 16 + fr;
      u16x8 t = *(const u16x8*)(&Bs[cur][o * 32 + (fq ^ ((o >> 1) & 3)) * 8]);
      bfv[n] = __builtin_bit_cast(bf16x8, t);
    }
#pragma unroll
    for (int m = 0; m < 2; ++m)
#pragma unroll
      for (int n = 0; n < 4; ++n)
        acc[m][n] = __builtin_amdgcn_mfma_f32_16x16x32_bf16(af[m], bfv[n], acc[m][n], 0, 0, 0);
    if (more) writeA(nxt, pa);
    __syncthreads();
    cur = nxt;
  }

  // ---- epilogue: bias + f32 store ----
  float bz[4];
#pragma unroll
  for (int n = 0; n < 4; ++n) bz[n] = bias[wc * 64 + n * 16 + fr];
#pragma unroll
  for (int m = 0; m < 2; ++m) {
#pragma unroll
    for (int reg = 0; reg < 4; ++reg) {
      const int grow = row0 + wr * 32 + m * 16 + fq * 4 + reg;
      const int bb = grow >> LOG2T;
      const int to = grow & (T - 1);
      float* op = out + ((long)bb * OUT_T + OUT0 + to) * EMB + wc * 64 + fr;
#pragma unroll
      for (int n = 0; n < 4; ++n) op[n * 16] = acc[m][n][reg] + bz[n];
    }
  }
}

__global__ __launch_bounds__(512, 4) void conv_fused(
    const int* __restrict__ value, const int* __restrict__ position,
    const float* __restrict__ ve3, const float* __restrict__ pe3,
    const u16* __restrict__ wt3, const float* __restrict__ w3, const float* __restrict__ b3,
    const float* __restrict__ ve4, const float* __restrict__ pe4,
    const u16* __restrict__ wt4, const float* __restrict__ w4, const float* __restrict__ b4,
    float* __restrict__ out) {
  __shared__ __align__(16) u16 As[2][64 * 32];
  __shared__ __align__(16) u16 Bs[2][256 * 32];
  __shared__ __align__(16) unsigned idxc[64 * 8];
  // interleave layers so long (K=2048) and short (K=1024) blocks mix on CUs:
  // bid%5==0 -> layer3 (128 blocks), else layer4 (512 blocks)
  const int g = blockIdx.x / 5, r = blockIdx.x % 5;
  if (r == 0)
    conv_tile<1024, 10, 4, 584, 584>(g, value, position, ve3, pe3,
                                     wt3, w3, b3, out, As, Bs, idxc);
  else
    conv_tile<2048, 12, 8, 4680, 1608>(g * 4 + (r - 1), value, position, ve4,
                                       pe4, wt4, w4, b4, out, As, Bs, idxc);
}

extern "C" void kernel_launch(void* const* d_in, const int* in_sizes, int n_in,
                              void* d_out, int out_size, void* d_ws, size_t ws_size,
                              hipStream_t stream) {
  const int* value = (const int*)d_in[0];
  const int* depth = (const int*)d_in[1];
  const int* position = (const int*)d_in[2];
  const float* ve0 = (const float*)d_in[3];
  const float* pe0 = (const float*)d_in[4];
  const float* ve1 = (const float*)d_in[5];
  const float* pe1 = (const float*)d_in[6];
  const float* ve2 = (const float*)d_in[7];
  const float* pe2 = (const float*)d_in[8];
  const float* ve3 = (const float*)d_in[9];
  const float* pe3 = (const float*)d_in[10];
  const float* ve4 = (const float*)d_in[11];
  const float* pe4 = (const float*)d_in[12];
  const float* de0 = (const float*)d_in[13];
  const float* de1 = (const float*)d_in[14];
  const float* de2 = (const float*)d_in[15];
  const float* w3 = (const float*)d_in[16];
  const float* b3 = (const float*)d_in[17];
  const float* w4 = (const float*)d_in[18];
  const float* b4 = (const float*)d_in[19];
  float* out = (float*)d_out;

  u16* wt3 = nullptr;
  u16* wt4 = nullptr;
  if (ws_size >= (size_t)(256 * 1024 + 256 * 2048) * sizeof(u16)) {
    wt3 = (u16*)d_ws;
    wt4 = wt3 + 256 * 1024;
    transpose_w<<<(256 * 2048) / 256, 256, 0, stream>>>(w3, w4, wt3, wt4);
  }
  emb_small<<<8 * 584, 256, 0, stream>>>(value, depth, position, ve0, pe0, de0,
                                         ve1, pe1, de1, ve2, pe2, de2, out);
  conv_fused<<<640, 512, 0, stream>>>(value, position, ve3, pe3, wt3, w3,
                                      b3, ve4, pe4, wt4, w4, b4, out);
}

// Round 5
// 84.528 us; speedup vs baseline: 1.5761x; 1.5761x over previous
//
#include <hip/hip_runtime.h>

#define S_TOT 37448
#define OUT_T 5704
#define EMB 256

typedef unsigned short u16;
typedef __bf16 bf16x8 __attribute__((ext_vector_type(8)));
typedef float f32x4 __attribute__((ext_vector_type(4)));
typedef unsigned short u16x4 __attribute__((ext_vector_type(4)));
typedef unsigned short u16x8 __attribute__((ext_vector_type(8)));

__device__ __forceinline__ u16 f2bf(float f) {
  union { float f; unsigned int i; } v;
  v.f = f;
  unsigned int x = v.i;
  return (u16)((x + 0x7fffu + ((x >> 16) & 1u)) >> 16);
}

#define GLOAD_LDS16(g, l)                                                     \
  __builtin_amdgcn_global_load_lds((const __attribute__((address_space(1))) void*)(g), \
                                   (__attribute__((address_space(3))) void*)(l), 16, 0, 0)

// ---------------- layers 0-2: pure embedding gather (f32, exact) ------------
__global__ __launch_bounds__(256) void emb_small(
    const int* __restrict__ value, const int* __restrict__ depth,
    const int* __restrict__ position,
    const float* __restrict__ ve0, const float* __restrict__ pe0, const float* __restrict__ de0,
    const float* __restrict__ ve1, const float* __restrict__ pe1, const float* __restrict__ de1,
    const float* __restrict__ ve2, const float* __restrict__ pe2, const float* __restrict__ de2,
    float* __restrict__ out) {
  const int tok = blockIdx.x;
  const int b = tok / 584;
  const int t = tok - b * 584;
  const float *ve, *pe, *de;
  if (t < 8)       { ve = ve0; pe = pe0; de = de0; }
  else if (t < 72) { ve = ve1; pe = pe1; de = de1; }
  else             { ve = ve2; pe = pe2; de = de2; }
  const long base = (long)b * S_TOT + t;
  const int v = value[base];
  const int d = depth[base];
  const int p0 = position[base * 3 + 0];
  const int p1 = position[base * 3 + 1];
  const int p2 = position[base * 3 + 2];
  const int e = threadIdx.x;
  const float sum = ve[v * EMB + e] + pe[p0 * EMB + e] +
                    pe[(64 + p1) * EMB + e] + pe[(128 + p2) * EMB + e] +
                    de[d * EMB + e];
  out[((long)b * OUT_T + t) * EMB + e] = sum;
}

// ------- W repack: f32 (O,E,k) -> bf16 Wt[o][kk*256+e] ----------------------
__global__ __launch_bounds__(256) void transpose_w(
    const float* __restrict__ w3, const float* __restrict__ w4,
    u16* __restrict__ wt3, u16* __restrict__ wt4) {
  const int i = blockIdx.x * 256 + threadIdx.x;
  if (i < 256 * 1024) {
    const int o = i >> 10, c = i & 1023, kk = c >> 8, e = c & 255;
    wt3[i] = f2bf(w3[o * 1024 + e * 4 + kk]);
  }
  if (i < 256 * 2048) {
    const int o = i >> 11, c = i & 2047, kk = c >> 8, e = c & 255;
    wt4[i] = f2bf(w4[o * 2048 + e * 8 + kk]);
  }
}

// ------- Projected tables: P_kk = W_kk @ [ve; pe0; pe1; pe2] ----------------
// For each (layer, kk): rows 0..3 = ve, 4..67 = pe0, 68..131 = pe1,
// 132..195 = pe2 (rows 196..255 padded garbage, never read).
// Output bf16 [256 rows][256 o] per (layer,kk).
__global__ __launch_bounds__(512) void proj_tables(
    const float* __restrict__ ve3, const float* __restrict__ pe3, const u16* __restrict__ wt3,
    const float* __restrict__ ve4, const float* __restrict__ pe4, const u16* __restrict__ wt4,
    u16* __restrict__ T3, u16* __restrict__ T4) {
  __shared__ __align__(16) u16 As[64 * 32];
  __shared__ __align__(16) u16 Bs[256 * 32];
  const int bid = blockIdx.x;  // 0..47
  const int p = bid >> 2, rb = bid & 3;
  const float *ve, *pe;
  const u16* wt;
  u16* To;
  int K, kk;
  if (p < 4) { ve = ve3; pe = pe3; wt = wt3; K = 1024; kk = p;     To = T3 + kk * 65536; }
  else       { ve = ve4; pe = pe4; wt = wt4; K = 2048; kk = p - 4; To = T4 + kk * 65536; }
  const int tid = threadIdx.x;
  const int lane = tid & 63, wid = tid >> 6;
  const int wr = wid >> 2, wc = wid & 3;
  const int fr = lane & 15, fq = lane >> 4;
  const int row0 = rb * 64;

  // A staging geometry: 8 threads/row, 4 cols each, XOR granule swizzle
  const int arow = tid >> 3, acg = tid & 7;
  const int agran = acg >> 1, ahalf = acg & 1;
  const int aoff = arow * 32 + (agran ^ ((arow >> 1) & 3)) * 8 + ahalf * 4;
  const int gr = row0 + arow;
  const int per = (gr - 4) < 191 ? (gr - 4) : 191;
  const float* asrc = (gr < 4) ? (ve + gr * 256) : (pe + per * 256);

  f32x4 acc[2][4];
#pragma unroll
  for (int m = 0; m < 2; ++m)
#pragma unroll
    for (int n = 0; n < 4; ++n) acc[m][n] = (f32x4){0.f, 0.f, 0.f, 0.f};

  for (int s = 0; s < 8; ++s) {
    // stage A (f32 table row -> bf16)
    {
      const float4 x = *(const float4*)(asrc + s * 32 + acg * 4);
      u16x4 pk;
      pk[0] = f2bf(x.x); pk[1] = f2bf(x.y); pk[2] = f2bf(x.z); pk[3] = f2bf(x.w);
      *(u16x4*)(&As[aoff]) = pk;
    }
    // stage B (async, pre-swizzled source, linear dest)
#pragma unroll
    for (int j = 0; j < 2; ++j) {
      const int rl = j * 128 + wid * 16 + (lane >> 2);
      const int gc = (lane & 3) ^ ((rl >> 1) & 3);
      const u16* src = wt + (long)rl * K + (kk * 8 + s) * 32 + gc * 8;
      u16* dst = &Bs[(j * 128 + wid * 16) * 32];
      GLOAD_LDS16(src, dst);
    }
    __syncthreads();
    bf16x8 af[2], bfv[4];
#pragma unroll
    for (int m = 0; m < 2; ++m) {
      const int r = wr * 32 + m * 16 + fr;
      u16x8 t = *(const u16x8*)(&As[r * 32 + (fq ^ ((r >> 1) & 3)) * 8]);
      af[m] = __builtin_bit_cast(bf16x8, t);
    }
#pragma unroll
    for (int n = 0; n < 4; ++n) {
      const int o = wc * 64 + n * 16 + fr;
      u16x8 t = *(const u16x8*)(&Bs[o * 32 + (fq ^ ((o >> 1) & 3)) * 8]);
      bfv[n] = __builtin_bit_cast(bf16x8, t);
    }
#pragma unroll
    for (int m = 0; m < 2; ++m)
#pragma unroll
      for (int n = 0; n < 4; ++n)
        acc[m][n] = __builtin_amdgcn_mfma_f32_16x16x32_bf16(af[m], bfv[n], acc[m][n], 0, 0, 0);
    __syncthreads();
  }
#pragma unroll
  for (int m = 0; m < 2; ++m)
#pragma unroll
    for (int reg = 0; reg < 4; ++reg) {
      const int r = row0 + wr * 32 + m * 16 + fq * 4 + reg;
#pragma unroll
      for (int n = 0; n < 4; ++n)
        To[r * 256 + wc * 64 + n * 16 + fr] = f2bf(acc[m][n][reg]);
    }
}

// ------- main conv: pure gather-add over projected tables -------------------
template <int CK, int LOG2T, int S0, int OUT0>
__device__ __forceinline__ void gather_tile(
    int bid, const int* __restrict__ value, const int* __restrict__ position,
    const u16* __restrict__ Tp, const float* __restrict__ bias,
    float* __restrict__ out, unsigned* idxs) {
  constexpr int T = 1 << LOG2T;
  const int tid = threadIdx.x;
  const int row0 = bid * 64;
  // stage packed indices for the block's 64 rows x CK sub-tokens
  for (int e = tid; e < 64 * CK; e += 256) {
    const int r = e / CK, kk = e % CK;
    const int grow = row0 + r;
    const int b = grow >> LOG2T, to = grow & (T - 1);
    const long sidx = (long)b * S_TOT + (S0 + to * CK + kk);
    const int* pp = position + sidx * 3;
    idxs[e] = (unsigned)value[sidx] | ((unsigned)pp[0] << 8) |
              ((unsigned)pp[1] << 16) | ((unsigned)pp[2] << 24);
  }
  __syncthreads();
  const int cp = tid & 127;  // column pair
  const int o0 = cp * 2;
  const int rg = tid >> 7;   // 0..1 row-group
  const float2 bz = *(const float2*)(bias + o0);
  for (int r0 = 0; r0 < 32; ++r0) {
    const int r = rg * 32 + r0;
    float s0 = bz.x, s1 = bz.y;
#pragma unroll
    for (int kk = 0; kk < CK; ++kk) {
      const unsigned q = idxs[r * CK + kk];
      const u16* tb = Tp + kk * 65536;
      const unsigned a0 = *(const unsigned*)(tb + (q & 255u) * 256 + o0);
      const unsigned a1 = *(const unsigned*)(tb + (4 + ((q >> 8) & 255u)) * 256 + o0);
      const unsigned a2 = *(const unsigned*)(tb + (68 + ((q >> 16) & 255u)) * 256 + o0);
      const unsigned a3 = *(const unsigned*)(tb + (132 + (q >> 24)) * 256 + o0);
      union { unsigned u; float f; } t;
      t.u = a0 << 16; s0 += t.f;
      t.u = a0 & 0xffff0000u; s1 += t.f;
      t.u = a1 << 16; s0 += t.f;
      t.u = a1 & 0xffff0000u; s1 += t.f;
      t.u = a2 << 16; s0 += t.f;
      t.u = a2 & 0xffff0000u; s1 += t.f;
      t.u = a3 << 16; s0 += t.f;
      t.u = a3 & 0xffff0000u; s1 += t.f;
    }
    const int grow = row0 + r;
    const int b = grow >> LOG2T, to = grow & (T - 1);
    *(float2*)(out + (long)(b * OUT_T + OUT0 + to) * 256 + o0) =
        make_float2(s0, s1);
  }
}

__global__ __launch_bounds__(256) void conv_gather(
    const int* __restrict__ value, const int* __restrict__ position,
    const u16* __restrict__ T3, const float* __restrict__ b3,
    const u16* __restrict__ T4, const float* __restrict__ b4,
    float* __restrict__ out) {
  __shared__ unsigned idxs[64 * 8];
  const int g = blockIdx.x / 5, r = blockIdx.x % 5;
  if (r == 0)
    gather_tile<4, 10, 584, 584>(g, value, position, T3, b3, out, idxs);
  else
    gather_tile<8, 12, 4680, 1608>(g * 4 + (r - 1), value, position, T4, b4,
                                   out, idxs);
}

// ================= FALLBACK (round-4 path, used if ws too small) ============
template <int K, int LOG2T, int CK, int S0, int OUT0>
__device__ __forceinline__ void conv_tile(
    int bid, const int* __restrict__ value, const int* __restrict__ position,
    const float* __restrict__ ve, const float* __restrict__ pe,
    const u16* __restrict__ wt, const float* __restrict__ wraw,
    const float* __restrict__ bias, float* __restrict__ out,
    u16 (*As)[64 * 32], u16 (*Bs)[256 * 32], unsigned* idxc) {
  constexpr int T = 1 << LOG2T;
  constexpr int NS = K / 32;
  const int tid = threadIdx.x;
  const int lane = tid & 63;
  const int wid = tid >> 6;
  const int wr = wid >> 2;
  const int wc = wid & 3;
  const int fr = lane & 15;
  const int fq = lane >> 4;
  const int row0 = bid * 64;
  for (int e = tid; e < 64 * CK; e += 512) {
    const int r = e / CK, kk = e % CK;
    const int grow = row0 + r;
    const int b = grow >> LOG2T;
    const int to = grow & (T - 1);
    const long sidx = (long)b * S_TOT + (S0 + to * CK + kk);
    const unsigned v = (unsigned)value[sidx];
    const int* pp = position + sidx * 3;
    idxc[e] = v | ((unsigned)pp[0] << 8) | ((unsigned)pp[1] << 16) |
              ((unsigned)pp[2] << 24);
  }
  __syncthreads();
  const int arow = tid >> 3;
  const int acg = tid & 7;
  const int agran = acg >> 1, ahalf = acg & 1;
  const int aoff = arow * 32 + (agran ^ ((arow >> 1) & 3)) * 8 + ahalf * 4;
  auto gatherA = [&](int s, float4& r) {
    const int kk = s >> 3;
    const int e0 = (s & 7) * 32 + acg * 4;
    const unsigned q = idxc[arow * CK + kk];
    const int v = q & 255, p0 = (q >> 8) & 255, p1 = (q >> 16) & 255, p2 = q >> 24;
    float4 x = *(const float4*)(ve + v * EMB + e0);
    float4 y = *(const float4*)(pe + p0 * EMB + e0);
    float4 z = *(const float4*)(pe + (64 + p1) * EMB + e0);
    float4 u = *(const float4*)(pe + (128 + p2) * EMB + e0);
    r.x = x.x + y.x + z.x + u.x;
    r.y = x.y + y.y + z.y + u.y;
    r.z = x.z + y.z + z.z + u.z;
    r.w = x.w + y.w + z.w + u.w;
  };
  auto writeA = [&](int buf, const float4& r) {
    u16x4 p;
    p[0] = f2bf(r.x); p[1] = f2bf(r.y); p[2] = f2bf(r.z); p[3] = f2bf(r.w);
    *(u16x4*)(&As[buf][aoff]) = p;
  };
  auto issueB = [&](int s, int buf) {
    if (wt) {
#pragma unroll
      for (int j = 0; j < 2; ++j) {
        const int rl = j * 128 + wid * 16 + (lane >> 2);
        const int sl = lane & 3;
        const int gc = sl ^ ((rl >> 1) & 3);
        const u16* src = wt + (long)rl * K + s * 32 + gc * 8;
        u16* dst = &Bs[buf][(j * 128 + wid * 16) * 32];
        GLOAD_LDS16(src, dst);
      }
    } else {
      const int o = tid >> 1;
      const int hr = tid & 1;
      const int kk = s >> 3, e0 = (s & 7) * 32;
      const int osw = (o >> 1) & 3;
#pragma unroll
      for (int g2 = 0; g2 < 2; ++g2) {
        const int g = hr * 2 + g2;
        u16x8 r;
#pragma unroll
        for (int c = 0; c < 8; ++c)
          r[c] = f2bf(wraw[(long)o * (EMB * CK) + (e0 + g * 8 + c) * CK + kk]);
        *(u16x8*)(&Bs[buf][o * 32 + (g ^ osw) * 8]) = r;
      }
    }
  };
  f32x4 acc[2][4];
#pragma unroll
  for (int m = 0; m < 2; ++m)
#pragma unroll
    for (int n = 0; n < 4; ++n) acc[m][n] = (f32x4){0.f, 0.f, 0.f, 0.f};
  {
    float4 a0;
    gatherA(0, a0);
    issueB(0, 0);
    writeA(0, a0);
  }
  __syncthreads();
  int cur = 0;
  for (int s = 0; s < NS; ++s) {
    const int nxt = cur ^ 1;
    const bool more = (s + 1 < NS);
    float4 pa;
    if (more) {
      gatherA(s + 1, pa);
      issueB(s + 1, nxt);
    }
    bf16x8 af[2], bfv[4];
#pragma unroll
    for (int m = 0; m < 2; ++m) {
      const int r = wr * 32 + m * 16 + fr;
      u16x8 t = *(const u16x8*)(&As[cur][r * 32 + (fq ^ ((r >> 1) & 3)) * 8]);
      af[m] = __builtin_bit_cast(bf16x8, t);
    }
#pragma unroll
    for (int n = 0; n < 4; ++n) {
      const int o = wc * 64 + n * 16 + fr;
      u16x8 t = *(const u16x8*)(&Bs[cur][o * 32 + (fq ^ ((o >> 1) & 3)) * 8]);
      bfv[n] = __builtin_bit_cast(bf16x8, t);
    }
#pragma unroll
    for (int m = 0; m < 2; ++m)
#pragma unroll
      for (int n = 0; n < 4; ++n)
        acc[m][n] = __builtin_amdgcn_mfma_f32_16x16x32_bf16(af[m], bfv[n], acc[m][n], 0, 0, 0);
    if (more) writeA(nxt, pa);
    __syncthreads();
    cur = nxt;
  }
  float bz[4];
#pragma unroll
  for (int n = 0; n < 4; ++n) bz[n] = bias[wc * 64 + n * 16 + fr];
#pragma unroll
  for (int m = 0; m < 2; ++m) {
#pragma unroll
    for (int reg = 0; reg < 4; ++reg) {
      const int grow = row0 + wr * 32 + m * 16 + fq * 4 + reg;
      const int bb = grow >> LOG2T;
      const int to = grow & (T - 1);
      float* op = out + ((long)bb * OUT_T + OUT0 + to) * EMB + wc * 64 + fr;
#pragma unroll
      for (int n = 0; n < 4; ++n) op[n * 16] = acc[m][n][reg] + bz[n];
    }
  }
}

__global__ __launch_bounds__(512, 4) void conv_fused(
    const int* __restrict__ value, const int* __restrict__ position,
    const float* __restrict__ ve3, const float* __restrict__ pe3,
    const u16* __restrict__ wt3, const float* __restrict__ w3, const float* __restrict__ b3,
    const float* __restrict__ ve4, const float* __restrict__ pe4,
    const u16* __restrict__ wt4, const float* __restrict__ w4, const float* __restrict__ b4,
    float* __restrict__ out) {
  __shared__ __align__(16) u16 As[2][64 * 32];
  __shared__ __align__(16) u16 Bs[2][256 * 32];
  __shared__ __align__(16) unsigned idxc[64 * 8];
  const int g = blockIdx.x / 5, r = blockIdx.x % 5;
  if (r == 0)
    conv_tile<1024, 10, 4, 584, 584>(g, value, position, ve3, pe3,
                                     wt3, w3, b3, out, As, Bs, idxc);
  else
    conv_tile<2048, 12, 8, 4680, 1608>(g * 4 + (r - 1), value, position, ve4,
                                       pe4, wt4, w4, b4, out, As, Bs, idxc);
}

extern "C" void kernel_launch(void* const* d_in, const int* in_sizes, int n_in,
                              void* d_out, int out_size, void* d_ws, size_t ws_size,
                              hipStream_t stream) {
  const int* value = (const int*)d_in[0];
  const int* depth = (const int*)d_in[1];
  const int* position = (const int*)d_in[2];
  const float* ve0 = (const float*)d_in[3];
  const float* pe0 = (const float*)d_in[4];
  const float* ve1 = (const float*)d_in[5];
  const float* pe1 = (const float*)d_in[6];
  const float* ve2 = (const float*)d_in[7];
  const float* pe2 = (const float*)d_in[8];
  const float* ve3 = (const float*)d_in[9];
  const float* pe3 = (const float*)d_in[10];
  const float* ve4 = (const float*)d_in[11];
  const float* pe4 = (const float*)d_in[12];
  const float* de0 = (const float*)d_in[13];
  const float* de1 = (const float*)d_in[14];
  const float* de2 = (const float*)d_in[15];
  const float* w3 = (const float*)d_in[16];
  const float* b3 = (const float*)d_in[17];
  const float* w4 = (const float*)d_in[18];
  const float* b4 = (const float*)d_in[19];
  float* out = (float*)d_out;

  u16* wt3 = (u16*)d_ws;
  u16* wt4 = wt3 + 256 * 1024;
  u16* T3 = wt4 + 256 * 2048;
  u16* T4 = T3 + 4 * 65536;
  const size_t need = (size_t)(256 * 1024 + 256 * 2048 + 12 * 65536) * sizeof(u16);

  emb_small<<<8 * 584, 256, 0, stream>>>(value, depth, position, ve0, pe0, de0,
                                         ve1, pe1, de1, ve2, pe2, de2, out);
  if (ws_size >= need) {
    transpose_w<<<(256 * 2048) / 256, 256, 0, stream>>>(w3, w4, wt3, wt4);
    proj_tables<<<48, 512, 0, stream>>>(ve3, pe3, wt3, ve4, pe4, wt4, T3, T4);
    conv_gather<<<640, 256, 0, stream>>>(value, position, T3, b3, T4, b4, out);
  } else {
    const bool havew = ws_size >= (size_t)(256 * 1024 + 256 * 2048) * sizeof(u16);
    if (havew)
      transpose_w<<<(256 * 2048) / 256, 256, 0, stream>>>(w3, w4, wt3, wt4);
    conv_fused<<<640, 512, 0, stream>>>(value, position, ve3, pe3,
                                        havew ? wt3 : nullptr, w3, b3, ve4, pe4,
                                        havew ? wt4 : nullptr, w4, b4, out);
  }
}